// Round 1
// 418.307 us; speedup vs baseline: 1.0523x; 1.0523x over previous
//
#include <hip/hip_runtime.h>

// AttnBlock B=32, C=512, N=1024. All GEMMs via bf16 MFMA 16x16x32.
// 256x256 tile, BK=64, 8 waves (2M x 4N), 128KB LDS double-buffer,
// 8-phase schedule with counted vmcnt(4) + setprio (T2+T3+T4+T5).
// Layouts: h[b][n][c], q[b][n][c], k[b][n][c], v[b][c][n], O[b][n][c].
// GEMM: C[m][n] = sum_k A[m][k]*B[n][k]  (A: MxK rm, B: NxK rm, K-contig)

#define C_DIM 512
#define N_PIX 1024
#define BATCH 32
#define CPG 16
#define EPS 1e-6f
#define SCALE 0.044194173824159216f  // 512^-0.5
#define ESTRIDE 66                   // epilogue LDS row stride (floats)

typedef unsigned short u16;
typedef __attribute__((ext_vector_type(8))) short bf16x8;
typedef __attribute__((ext_vector_type(4))) float f32x4;
typedef __attribute__((ext_vector_type(2))) float f32x2;

static __device__ __forceinline__ float bf2f(u16 u) {
    union { unsigned int i; float f; } v; v.i = ((unsigned int)u) << 16; return v.f;
}
static __device__ __forceinline__ u16 f2bf(float f) {
    union { float f; unsigned int i; } v; v.f = f;
    unsigned int r = v.i + 0x7fffu + ((v.i >> 16) & 1u);
    return (u16)(r >> 16);
}

static __device__ __forceinline__ void gl_lds16(const u16* g, u16* l) {
    __builtin_amdgcn_global_load_lds(
        (const __attribute__((address_space(1))) unsigned int*)g,
        (__attribute__((address_space(3))) unsigned int*)l,
        16, 0, 0);
}

#define BAR()   __builtin_amdgcn_s_barrier()
// allow scalar/vector ALU (addr calc) to cross, pin all memory + MFMA
#define SCHED() __builtin_amdgcn_sched_barrier(0x7)

// ------------------------------------------------------------- weights->bf16
__global__ __launch_bounds__(256) void wconv_kernel(
        const float* __restrict__ wq, const float* __restrict__ wk,
        const float* __restrict__ wv, const float* __restrict__ wp,
        u16* __restrict__ out) {
    int i = blockIdx.x * 256 + threadIdx.x;
    int mat = i >> 16;
    const float* src = (mat == 0) ? wq : (mat == 1) ? wk : (mat == 2) ? wv : wp;
    float4 v = ((const float4*)src)[i & 65535];
    ushort4 o;
    o.x = f2bf(v.x); o.y = f2bf(v.y); o.z = f2bf(v.z); o.w = f2bf(v.w);
    *(ushort4*)&out[(size_t)i * 4] = o;
}

// ------------------------------------------------------------- GroupNorm
__global__ __launch_bounds__(256) void gn_kernel(
        const float* __restrict__ x, const float* __restrict__ gw,
        const float* __restrict__ gb, u16* __restrict__ h) {
    int blk = blockIdx.x;
    int b = blk >> 5, g = blk & 31;
    size_t base = ((size_t)(b * C_DIM + g * CPG)) * N_PIX;
    const float4* xv = (const float4*)(x + base);
    int tid = threadIdx.x;

    float s = 0.f, sq = 0.f;
    for (int i = tid; i < (CPG * N_PIX) / 4; i += 256) {
        float4 v = xv[i];
        s  += v.x + v.y + v.z + v.w;
        sq += v.x * v.x + v.y * v.y + v.z * v.z + v.w * v.w;
    }
    __shared__ float rs[256], rq[256];
    rs[tid] = s; rq[tid] = sq;
    __syncthreads();
    for (int off = 128; off > 0; off >>= 1) {
        if (tid < off) { rs[tid] += rs[tid + off]; rq[tid] += rq[tid + off]; }
        __syncthreads();
    }
    float mean = rs[0] * (1.0f / (CPG * N_PIX));
    float var  = rq[0] * (1.0f / (CPG * N_PIX)) - mean * mean;
    float inv  = rsqrtf(var + EPS);

    __shared__ u16 Ls[CPG * N_PIX];
    for (int i = tid; i < (CPG * N_PIX) / 4; i += 256) {
        int c_local = i >> 8;
        int c = g * CPG + c_local;
        float sc = gw[c] * inv;
        float sh = gb[c] - mean * sc;
        float4 v = xv[i];
        ushort4 o;
        o.x = f2bf(v.x * sc + sh); o.y = f2bf(v.y * sc + sh);
        o.z = f2bf(v.z * sc + sh); o.w = f2bf(v.w * sc + sh);
        *(ushort4*)&Ls[c_local * N_PIX + (i & 255) * 4] = o;
    }
    __syncthreads();
    u16* hb = h + (size_t)b * N_PIX * C_DIM + g * CPG;
    for (int n = tid; n < N_PIX; n += 256) {
        unsigned int pk[8];
#pragma unroll
        for (int j = 0; j < 8; ++j) {
            unsigned int lo = Ls[(2 * j) * N_PIX + n];
            unsigned int hi = Ls[(2 * j + 1) * N_PIX + n];
            pk[j] = lo | (hi << 16);
        }
        uint4* dst = (uint4*)(hb + (size_t)n * C_DIM);
        dst[0] = make_uint4(pk[0], pk[1], pk[2], pk[3]);
        dst[1] = make_uint4(pk[4], pk[5], pk[6], pk[7]);
    }
}

// ------------------------------------------------------------- MFMA GEMM
// MODE 0: q&k (z=mat*32+b), bf16 out +bias[col]
// MODE 1: v, bf16 out +bias[row]
// MODE 2: scores, bf16 out *SCALE
// MODE 3: pv, bf16 out
// MODE 4: proj, f32 out +bias[row]+resid

// MFMA quadrant: mq selects mt 0-3 / 4-7, nq selects nt 0-1 / 2-3
#define MM(mq, nq) do { \
    _Pragma("unroll") \
    for (int t_ = 0; t_ < 4; ++t_) { \
        _Pragma("unroll") \
        for (int n_ = 0; n_ < 2; ++n_) { \
            _Pragma("unroll") \
            for (int ks_ = 0; ks_ < 2; ++ks_) \
                acc[(mq)*4 + t_][(nq)*2 + n_] = \
                    __builtin_amdgcn_mfma_f32_16x16x32_bf16( \
                        af[t_][ks_], bf[(nq)*2 + n_][ks_], \
                        acc[(mq)*4 + t_][(nq)*2 + n_], 0, 0, 0); \
        } \
    } \
} while (0)

template <int MODE>
__global__ __launch_bounds__(512, 2) void gemm_kernel(
        const u16* __restrict__ A, const u16* __restrict__ B,
        void* __restrict__ Cv, void* __restrict__ Cv2,
        const float* __restrict__ bias, const float* __restrict__ bias2,
        const float* __restrict__ xres, int K,
        int rsA, int rsB, int rsC,
        long long bsA, long long bsB, long long bsC) {
    int bx = blockIdx.x, by = blockIdx.y, bz = blockIdx.z;
    int mat = 0, b = bz;
    if (MODE == 0) { mat = bz >> 5; b = bz & 31; }
    const u16* gA = A + (size_t)b * bsA + (size_t)by * 256 * rsA;
    const u16* gB;
    if (MODE == 0) gB = B + (size_t)mat * 262144 + (size_t)bx * 256 * rsB;
    else           gB = B + (size_t)b * bsB + (size_t)bx * 256 * rsB;
    void* out = (MODE == 0 && mat) ? Cv2 : Cv;
    const float* bi_p = (MODE == 0 && mat) ? bias2 : bias;

    // 128 KB: buf0 A[256][64] | buf0 B[256][64] | buf1 A | buf1 B
    __shared__ __align__(16) u16 smem[65536];

    int tid = threadIdx.x;
    int lane = tid & 63, wave = tid >> 6;
    int wm = wave >> 2, wn = wave & 3;            // 2 x 4 wave grid
    int quad = lane >> 4, l15 = lane & 15, l7 = lane & 7;
    int srow = tid >> 3;                          // 0..63 staging row
    int lg = (tid & 7) ^ (srow & 7);              // pre-swizzled source group

    const int nk = K >> 6;                        // K-tiles (BK=64)
    const int nit = nk >> 1;                      // 2 K-tiles per iteration

    // stage one 128x64 half-tile: 2 x global_load_lds(16B) per thread.
    // LDS row r, group p holds global col-group p^(r&7) (XOR swizzle).
    auto STG = [&](int buf, int isB, int h, int kt) {
        const u16* g = isB ? gB : gA;
        int rs = isB ? rsB : rsA;
        const u16* src = g + (size_t)(h * 128 + srow) * rs + (size_t)kt * 64 + lg * 8;
        u16* dst = &smem[buf * 32768 + isB * 16384 + (h * 128 + srow) * 64 + (tid & 7) * 8];
        gl_lds16(src, dst);
        gl_lds16(src + (size_t)64 * rs, dst + 4096);
    };
    // fragment reads: row (..+l15), col-group (ks*4+quad) via XOR-swizzle
    auto LDA = [&](int buf, int mq, int t, int ks) -> bf16x8 {
        return *(const bf16x8*)&smem[buf * 32768 +
            (wm * 128 + mq * 64 + t * 16 + l15) * 64 + (((ks * 4 + quad) ^ l7) << 3)];
    };
    auto LDB = [&](int buf, int nt, int ks) -> bf16x8 {
        return *(const bf16x8*)&smem[buf * 32768 + 16384 +
            (wn * 64 + nt * 16 + l15) * 64 + (((ks * 4 + quad) ^ l7) << 3)];
    };

    f32x4 acc[8][4];
#pragma unroll
    for (int mt = 0; mt < 8; ++mt)
#pragma unroll
        for (int nt = 0; nt < 4; ++nt)
            acc[mt][nt] = (f32x4){0.f, 0.f, 0.f, 0.f};
    bf16x8 af[4][2], bf[4][2];

    // ---- prologue: tile0 full (buf0), tile1 B-halves (buf1); 12 loads/thread
    STG(0, 1, 0, 0); STG(0, 1, 1, 0);
    STG(0, 0, 0, 0); STG(0, 0, 1, 0);
    STG(1, 1, 0, 1); STG(1, 1, 1, 1);
    asm volatile("s_waitcnt vmcnt(4)" ::: "memory");   // tile0 landed
    SCHED(); BAR(); SCHED();

    for (int it = 0; it < nit; ++it) {
        const bool s = (it + 1 < nit);               // prefetch guard
        const int k1 = 2 * it + 1, k2 = 2 * it + 2, k3 = 2 * it + 3;

        // phase 1: read af(buf0,mq0)+bf(nt0,1); stage A buf1 h0 (tile k1)
#pragma unroll
        for (int t = 0; t < 4; ++t)
#pragma unroll
            for (int ks = 0; ks < 2; ++ks) af[t][ks] = LDA(0, 0, t, ks);
#pragma unroll
        for (int n = 0; n < 2; ++n)
#pragma unroll
            for (int ks = 0; ks < 2; ++ks) bf[n][ks] = LDB(0, n, ks);
        STG(1, 0, 0, k1);
        SCHED(); BAR(); SCHED();
        __builtin_amdgcn_s_setprio(1); MM(0, 0); __builtin_amdgcn_s_setprio(0);
        SCHED(); BAR(); SCHED();

        // phase 2: read bf(nt2,3) buf0; stage A buf1 h1 (k1)
#pragma unroll
        for (int n = 2; n < 4; ++n)
#pragma unroll
            for (int ks = 0; ks < 2; ++ks) bf[n][ks] = LDB(0, n, ks);
        STG(1, 0, 1, k1);
        SCHED(); BAR(); SCHED();
        __builtin_amdgcn_s_setprio(1); MM(0, 1); __builtin_amdgcn_s_setprio(0);
        SCHED(); BAR(); SCHED();

        // phase 3: read af(buf0,mq1); stage B buf0 h0 (k2)
#pragma unroll
        for (int t = 0; t < 4; ++t)
#pragma unroll
            for (int ks = 0; ks < 2; ++ks) af[t][ks] = LDA(0, 1, t, ks);
        if (s) STG(0, 1, 0, k2);
        SCHED(); BAR(); SCHED();
        __builtin_amdgcn_s_setprio(1); MM(1, 1); __builtin_amdgcn_s_setprio(0);
        SCHED(); BAR(); SCHED();

        // phase 4: stage B buf0 h1 (k2); MFMA; counted vmcnt -> buf1 ready
        if (s) STG(0, 1, 1, k2);
        SCHED(); BAR(); SCHED();
        __builtin_amdgcn_s_setprio(1); MM(1, 0); __builtin_amdgcn_s_setprio(0);
        if (s) asm volatile("s_waitcnt vmcnt(4)" ::: "memory");
        else   asm volatile("s_waitcnt vmcnt(0)" ::: "memory");
        SCHED(); BAR(); SCHED();

        // phase 5: read af(buf1,mq0)+bf(nt0,1); stage A buf0 h0 (k2)
#pragma unroll
        for (int t = 0; t < 4; ++t)
#pragma unroll
            for (int ks = 0; ks < 2; ++ks) af[t][ks] = LDA(1, 0, t, ks);
#pragma unroll
        for (int n = 0; n < 2; ++n)
#pragma unroll
            for (int ks = 0; ks < 2; ++ks) bf[n][ks] = LDB(1, n, ks);
        if (s) STG(0, 0, 0, k2);
        SCHED(); BAR(); SCHED();
        __builtin_amdgcn_s_setprio(1); MM(0, 0); __builtin_amdgcn_s_setprio(0);
        SCHED(); BAR(); SCHED();

        // phase 6: read bf(nt2,3) buf1; stage A buf0 h1 (k2)
#pragma unroll
        for (int n = 2; n < 4; ++n)
#pragma unroll
            for (int ks = 0; ks < 2; ++ks) bf[n][ks] = LDB(1, n, ks);
        if (s) STG(0, 0, 1, k2);
        SCHED(); BAR(); SCHED();
        __builtin_amdgcn_s_setprio(1); MM(0, 1); __builtin_amdgcn_s_setprio(0);
        SCHED(); BAR(); SCHED();

        // phase 7: read af(buf1,mq1); stage B buf1 h0 (k3)
#pragma unroll
        for (int t = 0; t < 4; ++t)
#pragma unroll
            for (int ks = 0; ks < 2; ++ks) af[t][ks] = LDA(1, 1, t, ks);
        if (s) STG(1, 1, 0, k3);
        SCHED(); BAR(); SCHED();
        __builtin_amdgcn_s_setprio(1); MM(1, 1); __builtin_amdgcn_s_setprio(0);
        SCHED(); BAR(); SCHED();

        // phase 8: stage B buf1 h1 (k3); MFMA; counted vmcnt -> buf0 ready
        if (s) STG(1, 1, 1, k3);
        SCHED(); BAR(); SCHED();
        __builtin_amdgcn_s_setprio(1); MM(1, 0); __builtin_amdgcn_s_setprio(0);
        if (s) asm volatile("s_waitcnt vmcnt(4)" ::: "memory");
        SCHED(); BAR(); SCHED();
    }

    // epilogue: per-wave LDS transpose, then vectorized global stores.
    // C/D frag: col = l15 (+nt*16), row = quad*4+reg (+mt*16).
    float* ebw = (float*)smem + wave * (16 * ESTRIDE);
    int er = lane >> 4;             // read row group 0..3
    int ec4 = (lane & 15) * 4;      // read col 0,4,..60
    int colb = bx * 256 + wn * 64;
    int rowb = by * 256 + wm * 128;
#pragma unroll
    for (int mt = 0; mt < 8; ++mt) {
#pragma unroll
        for (int nt = 0; nt < 4; ++nt) {
            f32x4 a = acc[mt][nt];
#pragma unroll
            for (int reg = 0; reg < 4; ++reg)
                ebw[(quad * 4 + reg) * ESTRIDE + nt * 16 + l15] = a[reg];
        }
        // wave-private region: in-order LDS within a wave, no barrier needed
#pragma unroll
        for (int j = 0; j < 4; ++j) {
            int lr = er + 4 * j;
            f32x2 v0 = *(f32x2*)&ebw[lr * ESTRIDE + ec4];
            f32x2 v1 = *(f32x2*)&ebw[lr * ESTRIDE + ec4 + 2];
            int gr = rowb + mt * 16 + lr;
            int gc = colb + ec4;
            size_t cidx = (size_t)b * bsC + (size_t)gr * rsC + gc;
            if (MODE == 0) {
                float4 b4 = *(const float4*)&bi_p[gc];
                ushort4 st;
                st.x = f2bf(v0.x + b4.x); st.y = f2bf(v0.y + b4.y);
                st.z = f2bf(v1.x + b4.z); st.w = f2bf(v1.y + b4.w);
                *(ushort4*)&((u16*)out)[cidx] = st;
            } else if (MODE == 1) {
                float bi = bi_p[gr];
                ushort4 st;
                st.x = f2bf(v0.x + bi); st.y = f2bf(v0.y + bi);
                st.z = f2bf(v1.x + bi); st.w = f2bf(v1.y + bi);
                *(ushort4*)&((u16*)out)[cidx] = st;
            } else if (MODE == 2) {
                ushort4 st;
                st.x = f2bf(v0.x * SCALE); st.y = f2bf(v0.y * SCALE);
                st.z = f2bf(v1.x * SCALE); st.w = f2bf(v1.y * SCALE);
                *(ushort4*)&((u16*)out)[cidx] = st;
            } else if (MODE == 3) {
                ushort4 st;
                st.x = f2bf(v0.x); st.y = f2bf(v0.y);
                st.z = f2bf(v1.x); st.w = f2bf(v1.y);
                *(ushort4*)&((u16*)out)[cidx] = st;
            } else {
                float bi = bi_p[gr];
                float4 xr = *(const float4*)&xres[cidx];
                float4 st = make_float4(v0.x + bi + xr.x, v0.y + bi + xr.y,
                                        v1.x + bi + xr.z, v1.y + bi + xr.w);
                *(float4*)&((float*)out)[cidx] = st;
            }
        }
    }
}

// ------------------------------------------------------------- Softmax
// bf16 S row (1024) -> bf16 P in place.
__global__ __launch_bounds__(256) void softmax_kernel(u16* __restrict__ S) {
    size_t row = blockIdx.x;
    u16* p = S + row * N_PIX;
    int tid = threadIdx.x;
    ushort4 uv = *(ushort4*)&p[tid * 4];
    float4 v = make_float4(bf2f(uv.x), bf2f(uv.y), bf2f(uv.z), bf2f(uv.w));
    __shared__ float red[256];
    float m = fmaxf(fmaxf(v.x, v.y), fmaxf(v.z, v.w));
    red[tid] = m; __syncthreads();
    for (int off = 128; off > 0; off >>= 1) {
        if (tid < off) red[tid] = fmaxf(red[tid], red[tid + off]);
        __syncthreads();
    }
    float M = red[0];
    __syncthreads();
    float4 e;
    e.x = __expf(v.x - M); e.y = __expf(v.y - M);
    e.z = __expf(v.z - M); e.w = __expf(v.w - M);
    red[tid] = e.x + e.y + e.z + e.w; __syncthreads();
    for (int off = 128; off > 0; off >>= 1) {
        if (tid < off) red[tid] += red[tid + off];
        __syncthreads();
    }
    float inv = 1.0f / red[0];
    ushort4 st;
    st.x = f2bf(e.x * inv); st.y = f2bf(e.y * inv);
    st.z = f2bf(e.z * inv); st.w = f2bf(e.w * inv);
    *(ushort4*)&p[tid * 4] = st;
}

extern "C" void kernel_launch(void* const* d_in, const int* in_sizes, int n_in,
                              void* d_out, int out_size, void* d_ws, size_t ws_size,
                              hipStream_t stream) {
    const float* x    = (const float*)d_in[0];
    const float* gn_w = (const float*)d_in[1];
    const float* gn_b = (const float*)d_in[2];
    const float* wq   = (const float*)d_in[3];
    const float* bq   = (const float*)d_in[4];
    const float* wk   = (const float*)d_in[5];
    const float* bk   = (const float*)d_in[6];
    const float* wv   = (const float*)d_in[7];
    const float* bv   = (const float*)d_in[8];
    const float* wp   = (const float*)d_in[9];
    const float* bp   = (const float*)d_in[10];
    float* y = (float*)d_out;

    const size_t BCN = (size_t)BATCH * C_DIM * N_PIX;
    char* w = (char*)d_ws;
    u16* h  = (u16*)(w);                       // 33.5 MB; reused as S (16b chunk)
    u16* q  = (u16*)(w + 2 * BCN);
    u16* k  = (u16*)(w + 4 * BCN);
    u16* v  = (u16*)(w + 6 * BCN);
    u16* O  = (u16*)(w + 8 * BCN);
    u16* wb = (u16*)(w + 10 * BCN);            // 2 MB bf16 weights
    u16* wvb = wb + 524288, *wpb = wb + 786432;
    u16* S = h;

    const long long BS = 524288;               // per-batch elems
    const long long SB = 1048576;              // per-batch S elems

    wconv_kernel<<<1024, 256, 0, stream>>>(wq, wk, wv, wp, wb);
    gn_kernel<<<1024, 256, 0, stream>>>(x, gn_w, gn_b, h);

    // q,k[n][o] = h[n][c]*w[o][c] + b[o]   M=1024 N=512 K=512, z=mat*32+b
    gemm_kernel<0><<<dim3(2, 4, 64), 512, 0, stream>>>(
        h, wb, q, k, bq, bk, nullptr, 512, 512, 512, 512, BS, 0, BS);
    // v[c][n] = wv[c][c']*h[n][c'] + bv[c]  M=512 N=1024 K=512
    gemm_kernel<1><<<dim3(4, 2, 32), 512, 0, stream>>>(
        wvb, h, v, nullptr, bv, nullptr, nullptr, 512, 512, 512, 1024, 0, BS, BS);

    for (int b0 = 0; b0 < BATCH; b0 += 16) {
        // S[i][j] = SCALE * q[i][o]*k[j][o]  (bf16 out) M=N=1024 K=512
        gemm_kernel<2><<<dim3(4, 4, 16), 512, 0, stream>>>(
            q + (size_t)b0 * BS, k + (size_t)b0 * BS, S, nullptr,
            nullptr, nullptr, nullptr, 512, 512, 512, 1024, BS, BS, SB);
        softmax_kernel<<<16 * 1024, 256, 0, stream>>>(S);
        // O[i][c] = P[i][j]*v[c][j]  M=1024 N=512 K=1024
        gemm_kernel<3><<<dim3(2, 4, 16), 512, 0, stream>>>(
            S, v + (size_t)b0 * BS, O + (size_t)b0 * BS, nullptr,
            nullptr, nullptr, nullptr, 1024, 1024, 1024, 512, SB, BS, BS);
    }

    // y[o][n] = x + bp[o] + wp[o][c]*O[n][c]  M=512 N=1024 K=512
    gemm_kernel<4><<<dim3(4, 2, 32), 512, 0, stream>>>(
        wpb, O, y, nullptr, bp, nullptr, x, 512, 512, 512, 1024, 0, BS, BS);
}

// Round 2
// 358.957 us; speedup vs baseline: 1.2263x; 1.1653x over previous
//
#include <hip/hip_runtime.h>

// AttnBlock B=32, C=512, N=1024. All GEMMs via bf16 MFMA 16x16x32.
// 256x256 tile, BK=64, 8 waves (2M x 4N), 128KB LDS double-buffer,
// 8-phase schedule, counted vmcnt(4), setprio, XCD-chunked swizzle.
// Layouts: h[b][n][c], q[b][n][c], k[b][n][c], v[b][c][n], O[b][n][c].
// GEMM: C[m][n] = sum_k A[m][k]*B[n][k]  (A: MxK rm, B: NxK rm, K-contig)

#define C_DIM 512
#define N_PIX 1024
#define BATCH 32
#define CPG 16
#define EPS 1e-6f
#define SCALE 0.044194173824159216f  // 512^-0.5
#define ESTRIDE 66                   // f32 epilogue LDS row stride (floats)
#define ESTRU   72                   // bf16 epilogue LDS row stride (u16)

typedef unsigned short u16;
typedef __attribute__((ext_vector_type(8))) short bf16x8;
typedef __attribute__((ext_vector_type(4))) float f32x4;
typedef __attribute__((ext_vector_type(2))) float f32x2;

static __device__ __forceinline__ float bf2f(u16 u) {
    union { unsigned int i; float f; } v; v.i = ((unsigned int)u) << 16; return v.f;
}
static __device__ __forceinline__ u16 f2bf(float f) {
    union { float f; unsigned int i; } v; v.f = f;
    unsigned int r = v.i + 0x7fffu + ((v.i >> 16) & 1u);
    return (u16)(r >> 16);
}

static __device__ __forceinline__ void gl_lds16(const u16* g, u16* l) {
    __builtin_amdgcn_global_load_lds(
        (const __attribute__((address_space(1))) unsigned int*)g,
        (__attribute__((address_space(3))) unsigned int*)l,
        16, 0, 0);
}

#define BAR()   __builtin_amdgcn_s_barrier()
#define SCHED() __builtin_amdgcn_sched_barrier(0x7)

// ------------------------------------------------------------- weights->bf16
__global__ __launch_bounds__(256) void wconv_kernel(
        const float* __restrict__ wq, const float* __restrict__ wk,
        const float* __restrict__ wv, const float* __restrict__ wp,
        u16* __restrict__ out) {
    int i = blockIdx.x * 256 + threadIdx.x;
    int mat = i >> 16;
    const float* src = (mat == 0) ? wq : (mat == 1) ? wk : (mat == 2) ? wv : wp;
    float4 v = ((const float4*)src)[i & 65535];
    ushort4 o;
    o.x = f2bf(v.x); o.y = f2bf(v.y); o.z = f2bf(v.z); o.w = f2bf(v.w);
    *(ushort4*)&out[(size_t)i * 4] = o;
}

// ------------------------------------------------------------- GroupNorm
__global__ __launch_bounds__(256) void gn_kernel(
        const float* __restrict__ x, const float* __restrict__ gw,
        const float* __restrict__ gb, u16* __restrict__ h) {
    int blk = blockIdx.x;
    int b = blk >> 5, g = blk & 31;
    size_t base = ((size_t)(b * C_DIM + g * CPG)) * N_PIX;
    const float4* xv = (const float4*)(x + base);
    int tid = threadIdx.x;

    float s = 0.f, sq = 0.f;
    for (int i = tid; i < (CPG * N_PIX) / 4; i += 256) {
        float4 v = xv[i];
        s  += v.x + v.y + v.z + v.w;
        sq += v.x * v.x + v.y * v.y + v.z * v.z + v.w * v.w;
    }
    __shared__ float rs[256], rq[256];
    rs[tid] = s; rq[tid] = sq;
    __syncthreads();
    for (int off = 128; off > 0; off >>= 1) {
        if (tid < off) { rs[tid] += rs[tid + off]; rq[tid] += rq[tid + off]; }
        __syncthreads();
    }
    float mean = rs[0] * (1.0f / (CPG * N_PIX));
    float var  = rq[0] * (1.0f / (CPG * N_PIX)) - mean * mean;
    float inv  = rsqrtf(var + EPS);

    __shared__ u16 Ls[CPG * N_PIX];
    for (int i = tid; i < (CPG * N_PIX) / 4; i += 256) {
        int c_local = i >> 8;
        int c = g * CPG + c_local;
        float sc = gw[c] * inv;
        float sh = gb[c] - mean * sc;
        float4 v = xv[i];
        ushort4 o;
        o.x = f2bf(v.x * sc + sh); o.y = f2bf(v.y * sc + sh);
        o.z = f2bf(v.z * sc + sh); o.w = f2bf(v.w * sc + sh);
        *(ushort4*)&Ls[c_local * N_PIX + (i & 255) * 4] = o;
    }
    __syncthreads();
    u16* hb = h + (size_t)b * N_PIX * C_DIM + g * CPG;
    for (int n = tid; n < N_PIX; n += 256) {
        unsigned int pk[8];
#pragma unroll
        for (int j = 0; j < 8; ++j) {
            unsigned int lo = Ls[(2 * j) * N_PIX + n];
            unsigned int hi = Ls[(2 * j + 1) * N_PIX + n];
            pk[j] = lo | (hi << 16);
        }
        uint4* dst = (uint4*)(hb + (size_t)n * C_DIM);
        dst[0] = make_uint4(pk[0], pk[1], pk[2], pk[3]);
        dst[1] = make_uint4(pk[4], pk[5], pk[6], pk[7]);
    }
}

// ------------------------------------------------------------- MFMA GEMM
// MODE 0: q&k (z=2b+mat), bf16 out +bias[col]
// MODE 1: v, bf16 out +bias[row]
// MODE 2: scores z=32 (S0/S1 halves), bf16 out *SCALE
// MODE 3: pv z=32 (A=S0/S1, out=O0/O1), bf16 out
// MODE 4: proj z=32 (B=O0/O1), f32 out +bias[row]+resid

#define MM(mq, nq) do { \
    _Pragma("unroll") \
    for (int t_ = 0; t_ < 4; ++t_) { \
        _Pragma("unroll") \
        for (int n_ = 0; n_ < 2; ++n_) { \
            _Pragma("unroll") \
            for (int ks_ = 0; ks_ < 2; ++ks_) \
                acc[(mq)*4 + t_][(nq)*2 + n_] = \
                    __builtin_amdgcn_mfma_f32_16x16x32_bf16( \
                        af[t_][ks_], bf[(nq)*2 + n_][ks_], \
                        acc[(mq)*4 + t_][(nq)*2 + n_], 0, 0, 0); \
        } \
    } \
} while (0)

template <int MODE>
__global__ __launch_bounds__(512, 2) void gemm_kernel(
        const u16* __restrict__ A, const u16* __restrict__ A2,
        const u16* __restrict__ B, const u16* __restrict__ B2,
        void* __restrict__ Cv, void* __restrict__ Cv2,
        const float* __restrict__ bias, const float* __restrict__ bias2,
        const float* __restrict__ xres, int K,
        int rsA, int rsB, int rsC,
        long long bsA, long long bsB, long long bsC) {
    // XCD-chunked bijective swizzle: blocks with flat%8 (one XCD) process
    // a contiguous chunk of tile ids -> same-panel sharers colocate in L2.
    int nx = gridDim.x, ny = gridDim.y;
    int nwg = nx * ny * gridDim.z;
    int flat = blockIdx.x + nx * (blockIdx.y + ny * blockIdx.z);
    int t = (flat & 7) * (nwg >> 3) + (flat >> 3);
    int bx = t % nx, by = (t / nx) % ny, bz = t / (nx * ny);

    int mat = 0, b = bz;
    const u16 *gA, *gB;
    void* out = Cv;
    const float* bi_p = bias;
    if (MODE == 0) {
        mat = bz & 1; b = bz >> 1;
        gA = A + (size_t)b * bsA + (size_t)by * 256 * rsA;
        gB = B + (size_t)mat * 262144 + (size_t)bx * 256 * rsB;
        out = mat ? Cv2 : Cv;
        bi_p = mat ? bias2 : bias;
    } else if (MODE == 2) {
        gA = A + (size_t)b * bsA + (size_t)by * 256 * rsA;
        gB = B + (size_t)b * bsB + (size_t)bx * 256 * rsB;
        out = (b >= 16) ? Cv2 : Cv;
    } else if (MODE == 3) {
        gA = ((b >= 16) ? A2 : A) + (size_t)(b & 15) * bsA + (size_t)by * 256 * rsA;
        gB = B + (size_t)b * bsB + (size_t)bx * 256 * rsB;
        out = (b >= 16) ? Cv2 : Cv;
    } else if (MODE == 4) {
        gA = A + (size_t)by * 256 * rsA;
        gB = ((b >= 16) ? B2 : B) + (size_t)(b & 15) * bsB + (size_t)bx * 256 * rsB;
    } else {  // MODE 1
        gA = A + (size_t)by * 256 * rsA;
        gB = B + (size_t)b * bsB + (size_t)bx * 256 * rsB;
    }
    int cb = (MODE == 2 || MODE == 3) ? (b & 15) : b;   // batch idx for C

    // 128 KB: buf0 A[256][64] | buf0 B[256][64] | buf1 A | buf1 B
    __shared__ __align__(16) u16 smem[65536];

    int tid = threadIdx.x;
    int lane = tid & 63, wave = tid >> 6;
    int wm = wave >> 2, wn = wave & 3;            // 2 x 4 wave grid
    int quad = lane >> 4, l15 = lane & 15, l7 = lane & 7;
    int srow = tid >> 3;                          // 0..63 staging row
    int lg = (tid & 7) ^ (srow & 7);              // pre-swizzled source group

    const int nk = K >> 6;                        // K-tiles (BK=64)
    const int nit = nk >> 1;                      // 2 K-tiles per iteration

    auto STG = [&](int buf, int isB, int h, int kt) {
        const u16* g = isB ? gB : gA;
        int rs = isB ? rsB : rsA;
        const u16* src = g + (size_t)(h * 128 + srow) * rs + (size_t)kt * 64 + lg * 8;
        u16* dst = &smem[buf * 32768 + isB * 16384 + (h * 128 + srow) * 64 + (tid & 7) * 8];
        gl_lds16(src, dst);
        gl_lds16(src + (size_t)64 * rs, dst + 4096);
    };
    auto LDA = [&](int buf, int mq, int t_, int ks) -> bf16x8 {
        return *(const bf16x8*)&smem[buf * 32768 +
            (wm * 128 + mq * 64 + t_ * 16 + l15) * 64 + (((ks * 4 + quad) ^ l7) << 3)];
    };
    auto LDB = [&](int buf, int nt, int ks) -> bf16x8 {
        return *(const bf16x8*)&smem[buf * 32768 + 16384 +
            (wn * 64 + nt * 16 + l15) * 64 + (((ks * 4 + quad) ^ l7) << 3)];
    };

    f32x4 acc[8][4];
#pragma unroll
    for (int mt = 0; mt < 8; ++mt)
#pragma unroll
        for (int nt = 0; nt < 4; ++nt)
            acc[mt][nt] = (f32x4){0.f, 0.f, 0.f, 0.f};
    bf16x8 af[4][2], bf[4][2];

    // ---- prologue: tile0 full (buf0), tile1 B-halves (buf1)
    STG(0, 1, 0, 0); STG(0, 1, 1, 0);
    STG(0, 0, 0, 0); STG(0, 0, 1, 0);
    STG(1, 1, 0, 1); STG(1, 1, 1, 1);
    asm volatile("s_waitcnt vmcnt(4)" ::: "memory");   // tile0 landed
    SCHED(); BAR(); SCHED();

    for (int it = 0; it < nit; ++it) {
        const bool s = (it + 1 < nit);
        const int k1 = 2 * it + 1, k2 = 2 * it + 2, k3 = 2 * it + 3;

        // phase 1
#pragma unroll
        for (int t_ = 0; t_ < 4; ++t_)
#pragma unroll
            for (int ks = 0; ks < 2; ++ks) af[t_][ks] = LDA(0, 0, t_, ks);
#pragma unroll
        for (int n = 0; n < 2; ++n)
#pragma unroll
            for (int ks = 0; ks < 2; ++ks) bf[n][ks] = LDB(0, n, ks);
        STG(1, 0, 0, k1);
        SCHED(); BAR(); SCHED();
        __builtin_amdgcn_s_setprio(1); MM(0, 0); __builtin_amdgcn_s_setprio(0);
        SCHED(); BAR(); SCHED();

        // phase 2
#pragma unroll
        for (int n = 2; n < 4; ++n)
#pragma unroll
            for (int ks = 0; ks < 2; ++ks) bf[n][ks] = LDB(0, n, ks);
        STG(1, 0, 1, k1);
        SCHED(); BAR(); SCHED();
        __builtin_amdgcn_s_setprio(1); MM(0, 1); __builtin_amdgcn_s_setprio(0);
        SCHED(); BAR(); SCHED();

        // phase 3
#pragma unroll
        for (int t_ = 0; t_ < 4; ++t_)
#pragma unroll
            for (int ks = 0; ks < 2; ++ks) af[t_][ks] = LDA(0, 1, t_, ks);
        if (s) STG(0, 1, 0, k2);
        SCHED(); BAR(); SCHED();
        __builtin_amdgcn_s_setprio(1); MM(1, 1); __builtin_amdgcn_s_setprio(0);
        SCHED(); BAR(); SCHED();

        // phase 4
        if (s) STG(0, 1, 1, k2);
        SCHED(); BAR(); SCHED();
        __builtin_amdgcn_s_setprio(1); MM(1, 0); __builtin_amdgcn_s_setprio(0);
        if (s) asm volatile("s_waitcnt vmcnt(4)" ::: "memory");
        else   asm volatile("s_waitcnt vmcnt(0)" ::: "memory");
        SCHED(); BAR(); SCHED();

        // phase 5
#pragma unroll
        for (int t_ = 0; t_ < 4; ++t_)
#pragma unroll
            for (int ks = 0; ks < 2; ++ks) af[t_][ks] = LDA(1, 0, t_, ks);
#pragma unroll
        for (int n = 0; n < 2; ++n)
#pragma unroll
            for (int ks = 0; ks < 2; ++ks) bf[n][ks] = LDB(1, n, ks);
        if (s) STG(0, 0, 0, k2);
        SCHED(); BAR(); SCHED();
        __builtin_amdgcn_s_setprio(1); MM(0, 0); __builtin_amdgcn_s_setprio(0);
        SCHED(); BAR(); SCHED();

        // phase 6
#pragma unroll
        for (int n = 2; n < 4; ++n)
#pragma unroll
            for (int ks = 0; ks < 2; ++ks) bf[n][ks] = LDB(1, n, ks);
        if (s) STG(0, 0, 1, k2);
        SCHED(); BAR(); SCHED();
        __builtin_amdgcn_s_setprio(1); MM(0, 1); __builtin_amdgcn_s_setprio(0);
        SCHED(); BAR(); SCHED();

        // phase 7
#pragma unroll
        for (int t_ = 0; t_ < 4; ++t_)
#pragma unroll
            for (int ks = 0; ks < 2; ++ks) af[t_][ks] = LDA(1, 1, t_, ks);
        if (s) STG(1, 1, 0, k3);
        SCHED(); BAR(); SCHED();
        __builtin_amdgcn_s_setprio(1); MM(1, 1); __builtin_amdgcn_s_setprio(0);
        SCHED(); BAR(); SCHED();

        // phase 8
        if (s) STG(1, 1, 1, k3);
        SCHED(); BAR(); SCHED();
        __builtin_amdgcn_s_setprio(1); MM(1, 0); __builtin_amdgcn_s_setprio(0);
        if (s) asm volatile("s_waitcnt vmcnt(4)" ::: "memory");
        SCHED(); BAR(); SCHED();
    }

    int colb = bx * 256 + wn * 64;
    int rowb = by * 256 + wm * 128;

    if (MODE == 4) {
        // f32 epilogue: LDS transpose at stride 66, float4 stores + bias + resid
        float* ebw = (float*)smem + wave * (16 * ESTRIDE);
        int er = lane >> 4;
        int ec4 = (lane & 15) * 4;
#pragma unroll
        for (int mt = 0; mt < 8; ++mt) {
#pragma unroll
            for (int nt = 0; nt < 4; ++nt) {
                f32x4 a = acc[mt][nt];
#pragma unroll
                for (int reg = 0; reg < 4; ++reg)
                    ebw[(quad * 4 + reg) * ESTRIDE + nt * 16 + l15] = a[reg];
            }
#pragma unroll
            for (int j = 0; j < 4; ++j) {
                int lr = er + 4 * j;
                f32x2 v0 = *(f32x2*)&ebw[lr * ESTRIDE + ec4];
                f32x2 v1 = *(f32x2*)&ebw[lr * ESTRIDE + ec4 + 2];
                int gr = rowb + mt * 16 + lr;
                int gc = colb + ec4;
                size_t cidx = (size_t)cb * bsC + (size_t)gr * rsC + gc;
                float bi = bi_p[gr];
                float4 xr = *(const float4*)&xres[cidx];
                float4 st = make_float4(v0.x + bi + xr.x, v0.y + bi + xr.y,
                                        v1.x + bi + xr.z, v1.y + bi + xr.w);
                *(float4*)&((float*)out)[cidx] = st;
            }
        }
    } else {
        // bf16 epilogue: bias/scale in-register, u16 LDS transpose (stride 72),
        // 16B coalesced stores.
        u16* ebw = (u16*)smem + wave * (16 * ESTRU);
        int er = lane >> 3;            // 0..7
        int ec = (lane & 7) * 8;       // col group
        float bcol[4];
        if (MODE == 0) {
#pragma unroll
            for (int nt = 0; nt < 4; ++nt)
                bcol[nt] = bi_p[colb + nt * 16 + l15];
        }
#pragma unroll
        for (int mt = 0; mt < 8; ++mt) {
            float4 brow;
            if (MODE == 1)
                brow = *(const float4*)&bi_p[rowb + mt * 16 + quad * 4];
#pragma unroll
            for (int nt = 0; nt < 4; ++nt) {
                f32x4 a = acc[mt][nt];
#pragma unroll
                for (int reg = 0; reg < 4; ++reg) {
                    float fv = a[reg];
                    if (MODE == 0) fv += bcol[nt];
                    else if (MODE == 1) fv += ((const float*)&brow)[reg];
                    else if (MODE == 2) fv *= SCALE;
                    ebw[(quad * 4 + reg) * ESTRU + nt * 16 + l15] = f2bf(fv);
                }
            }
#pragma unroll
            for (int j = 0; j < 2; ++j) {
                int lr = er + 8 * j;
                bf16x8 vv = *(const bf16x8*)&ebw[lr * ESTRU + ec];
                int gr = rowb + mt * 16 + lr;
                size_t cidx = (size_t)cb * bsC + (size_t)gr * rsC + colb + ec;
                *(bf16x8*)&((u16*)out)[cidx] = vv;
            }
        }
    }
}

// ------------------------------------------------------------- Softmax
// bf16 S row (1024) -> bf16 P in place. 32768 rows over two chunks.
__global__ __launch_bounds__(256) void softmax_kernel(
        u16* __restrict__ S0, u16* __restrict__ S1) {
    int row = blockIdx.x;
    u16* base = (row & 16384) ? S1 : S0;
    u16* p = base + (size_t)(row & 16383) * N_PIX;
    int tid = threadIdx.x;
    ushort4 uv = *(ushort4*)&p[tid * 4];
    float4 v = make_float4(bf2f(uv.x), bf2f(uv.y), bf2f(uv.z), bf2f(uv.w));
    __shared__ float red[256];
    float m = fmaxf(fmaxf(v.x, v.y), fmaxf(v.z, v.w));
    red[tid] = m; __syncthreads();
    for (int off = 128; off > 0; off >>= 1) {
        if (tid < off) red[tid] = fmaxf(red[tid], red[tid + off]);
        __syncthreads();
    }
    float M = red[0];
    __syncthreads();
    float4 e;
    e.x = __expf(v.x - M); e.y = __expf(v.y - M);
    e.z = __expf(v.z - M); e.w = __expf(v.w - M);
    red[tid] = e.x + e.y + e.z + e.w; __syncthreads();
    for (int off = 128; off > 0; off >>= 1) {
        if (tid < off) red[tid] += red[tid + off];
        __syncthreads();
    }
    float inv = 1.0f / red[0];
    ushort4 st;
    st.x = f2bf(e.x * inv); st.y = f2bf(e.y * inv);
    st.z = f2bf(e.z * inv); st.w = f2bf(e.w * inv);
    *(ushort4*)&p[tid * 4] = st;
}

extern "C" void kernel_launch(void* const* d_in, const int* in_sizes, int n_in,
                              void* d_out, int out_size, void* d_ws, size_t ws_size,
                              hipStream_t stream) {
    const float* x    = (const float*)d_in[0];
    const float* gn_w = (const float*)d_in[1];
    const float* gn_b = (const float*)d_in[2];
    const float* wq   = (const float*)d_in[3];
    const float* bq   = (const float*)d_in[4];
    const float* wk   = (const float*)d_in[5];
    const float* bk   = (const float*)d_in[6];
    const float* wv   = (const float*)d_in[7];
    const float* bv   = (const float*)d_in[8];
    const float* wp   = (const float*)d_in[9];
    const float* bp   = (const float*)d_in[10];
    float* y = (float*)d_out;

    const size_t BCN = (size_t)BATCH * C_DIM * N_PIX;
    char* w = (char*)d_ws;
    u16* h  = (u16*)(w);                       // 33.5 MB; reused as S0
    u16* q  = (u16*)(w + 2 * BCN);             // reused as O0
    u16* k  = (u16*)(w + 4 * BCN);             // reused as O1
    u16* v  = (u16*)(w + 6 * BCN);
    u16* Or = (u16*)(w + 8 * BCN);             // reused as S1
    u16* wb = (u16*)(w + 10 * BCN);            // 2 MB bf16 weights
    u16* wvb = wb + 524288, *wpb = wb + 786432;
    u16* S0 = h;
    u16* S1 = Or;
    u16* O0 = q;
    u16* O1 = k;

    const long long BS = 524288;               // per-batch elems
    const long long SB = 1048576;              // per-batch S elems

    wconv_kernel<<<1024, 256, 0, stream>>>(wq, wk, wv, wp, wb);
    gn_kernel<<<1024, 256, 0, stream>>>(x, gn_w, gn_b, h);

    // q,k[n][o] = h[n][c]*w[o][c] + b[o]   M=1024 N=512 K=512, z=2b+mat
    gemm_kernel<0><<<dim3(2, 4, 64), 512, 0, stream>>>(
        h, nullptr, wb, nullptr, q, k, bq, bk, nullptr,
        512, 512, 512, 512, BS, 0, BS);
    // v[c][n] = wv[c][c']*h[n][c'] + bv[c]  M=512 N=1024 K=512
    gemm_kernel<1><<<dim3(4, 2, 32), 512, 0, stream>>>(
        wvb, nullptr, h, nullptr, v, nullptr, bv, nullptr, nullptr,
        512, 512, 512, 1024, 0, BS, BS);

    // S[i][j] = SCALE * q[i][o]*k[j][o]  M=N=1024 K=512, all 32 batches
    gemm_kernel<2><<<dim3(4, 4, 32), 512, 0, stream>>>(
        q, nullptr, k, nullptr, S0, S1, nullptr, nullptr, nullptr,
        512, 512, 512, 1024, BS, BS, SB);
    softmax_kernel<<<32 * 1024, 256, 0, stream>>>(S0, S1);
    // O[i][c] = P[i][j]*v[c][j]  M=1024 N=512 K=1024, all 32 batches
    gemm_kernel<3><<<dim3(2, 4, 32), 512, 0, stream>>>(
        S0, S1, v, nullptr, O0, O1, nullptr, nullptr, nullptr,
        1024, 1024, 1024, 512, SB, BS, BS);

    // y[o][n] = x + bp[o] + wp[o][c]*O[n][c]  M=512 N=1024 K=512
    gemm_kernel<4><<<dim3(4, 2, 32), 512, 0, stream>>>(
        wpb, nullptr, O0, O1, y, nullptr, bp, nullptr, x,
        512, 512, 512, 1024, 0, BS, BS);
}

// Round 4
// 341.075 us; speedup vs baseline: 1.2906x; 1.0524x over previous
//
#include <hip/hip_runtime.h>

// AttnBlock B=32, C=512, N=1024. All GEMMs via bf16 MFMA 16x16x32.
// 256x256 tile, BK=64, 8 waves (2M x 4N), 128KB LDS double-buffer,
// 8-phase schedule, counted vmcnt, setprio, XCD-chunked swizzle,
// NT-tile persistence (tile2 prologue overlapped with tile1 tail+epilogue).
// Layouts: h[b][n][c], q[b][n][c], k[b][n][c], v[b][c][n], O[b][n][c].
// GEMM: C[m][n] = sum_k A[m][k]*B[n][k]  (A: MxK rm, B: NxK rm, K-contig)

#define C_DIM 512
#define N_PIX 1024
#define BATCH 32
#define CPG 16
#define EPS 1e-6f
#define SCALE 0.044194173824159216f  // 512^-0.5
#define ESTRIDE 66                   // f32 epilogue LDS row stride (floats)
#define ESTRU   72                   // bf16 epilogue LDS row stride (u16)

typedef unsigned short u16;
typedef __attribute__((ext_vector_type(8))) short bf16x8;
typedef __attribute__((ext_vector_type(4))) float f32x4;
typedef __attribute__((ext_vector_type(2))) float f32x2;

static __device__ __forceinline__ float bf2f(u16 u) {
    union { unsigned int i; float f; } v; v.i = ((unsigned int)u) << 16; return v.f;
}
static __device__ __forceinline__ u16 f2bf(float f) {
    union { float f; unsigned int i; } v; v.f = f;
    unsigned int r = v.i + 0x7fffu + ((v.i >> 16) & 1u);
    return (u16)(r >> 16);
}

static __device__ __forceinline__ void gl_lds16(const u16* g, u16* l) {
    __builtin_amdgcn_global_load_lds(
        (const __attribute__((address_space(1))) unsigned int*)g,
        (__attribute__((address_space(3))) unsigned int*)l,
        16, 0, 0);
}

#define BAR()   __builtin_amdgcn_s_barrier()
#define SCHED() __builtin_amdgcn_sched_barrier(0x7)

// ------------------------------------------------- weights->bf16 + GN stats
__global__ __launch_bounds__(256) void prep_kernel(
        const float* __restrict__ wq, const float* __restrict__ wk,
        const float* __restrict__ wv, const float* __restrict__ wp,
        u16* __restrict__ out, const float* __restrict__ x,
        float* __restrict__ stats) {
    int blk = blockIdx.x;
    if (blk < 1024) {   // weight convert
        int i = blk * 256 + threadIdx.x;
        int mat = i >> 16;
        const float* src = (mat == 0) ? wq : (mat == 1) ? wk : (mat == 2) ? wv : wp;
        float4 v = ((const float4*)src)[i & 65535];
        ushort4 o;
        o.x = f2bf(v.x); o.y = f2bf(v.y); o.z = f2bf(v.z); o.w = f2bf(v.w);
        *(ushort4*)&out[(size_t)i * 4] = o;
        return;
    }
    blk -= 1024;        // group-norm stats for (b,g)
    int b = blk >> 5, g = blk & 31;
    const float4* xv = (const float4*)(x + ((size_t)(b * C_DIM + g * CPG)) * N_PIX);
    int tid = threadIdx.x;
    float s = 0.f, sq = 0.f;
#pragma unroll 4
    for (int i = tid; i < (CPG * N_PIX) / 4; i += 256) {
        float4 v = xv[i];
        s  += v.x + v.y + v.z + v.w;
        sq += v.x * v.x + v.y * v.y + v.z * v.z + v.w * v.w;
    }
#pragma unroll
    for (int m = 1; m < 64; m <<= 1) {
        s += __shfl_xor(s, m);
        sq += __shfl_xor(sq, m);
    }
    __shared__ float rs[4], rq[4];
    int wv_ = tid >> 6;
    if ((tid & 63) == 0) { rs[wv_] = s; rq[wv_] = sq; }
    __syncthreads();
    if (tid == 0) {
        float S = rs[0] + rs[1] + rs[2] + rs[3];
        float Q = rq[0] + rq[1] + rq[2] + rq[3];
        float mean = S * (1.0f / (CPG * N_PIX));
        float var  = Q * (1.0f / (CPG * N_PIX)) - mean * mean;
        stats[blk * 2] = mean;
        stats[blk * 2 + 1] = rsqrtf(var + EPS);
    }
}

// ------------------------------------------------- GN transform (coalesced)
// block = (b, n-chunk of 64). LDS tile [64n][520c], coalesced 32B h-writes.
__global__ __launch_bounds__(256) void gnt_kernel(
        const float* __restrict__ x, const float* __restrict__ gw,
        const float* __restrict__ gb, const float* __restrict__ stats,
        u16* __restrict__ h) {
    int blk = blockIdx.x;
    int b = blk >> 4, nc = blk & 15;
    int n0 = nc * 64;
    __shared__ u16 T[64 * 520];
    int tid = threadIdx.x;
    int cq = tid >> 4;        // c offset within pass (0..15)
    int n4 = tid & 15;        // float4 index along n
    const float* xb = x + (size_t)b * C_DIM * N_PIX + n0;
#pragma unroll 4
    for (int pass = 0; pass < 32; ++pass) {
        int c = pass * 16 + cq;
        int g = c >> 4;
        float mean = stats[(b * 32 + g) * 2];
        float inv  = stats[(b * 32 + g) * 2 + 1];
        float sc = gw[c] * inv;
        float sh = gb[c] - mean * sc;
        float4 v = *(const float4*)(xb + (size_t)c * N_PIX + n4 * 4);
        int nn = n4 * 4;
        T[(nn + 0) * 520 + c] = f2bf(v.x * sc + sh);
        T[(nn + 1) * 520 + c] = f2bf(v.y * sc + sh);
        T[(nn + 2) * 520 + c] = f2bf(v.z * sc + sh);
        T[(nn + 3) * 520 + c] = f2bf(v.w * sc + sh);
    }
    __syncthreads();
    u16* hb = h + ((size_t)b * N_PIX + n0) * C_DIM;
    int rr = tid >> 5;            // 0..7
    int cc = (tid & 31) * 16;     // 0..496
#pragma unroll
    for (int p = 0; p < 8; ++p) {
        int n = p * 8 + rr;
        bf16x8 v0 = *(const bf16x8*)&T[n * 520 + cc];
        bf16x8 v1 = *(const bf16x8*)&T[n * 520 + cc + 8];
        *(bf16x8*)&hb[(size_t)n * C_DIM + cc] = v0;
        *(bf16x8*)&hb[(size_t)n * C_DIM + cc + 8] = v1;
    }
}

// ------------------------------------------------------------- MFMA GEMM
// MODE 0: q&k (z=2b+mat), bf16 out +bias[col]
// MODE 1: v, bf16 out +bias[row]
// MODE 2: scores (S0/S1 halves), bf16 out *SCALE
// MODE 3: pv (A=S0/S1, out=O0/O1), bf16 out
// MODE 4: proj (B=O0/O1), f32 out +bias[row]+resid
// NT = tiles per block (persistent): grid is always 256 blocks.

#define MM(mq, nq) do { \
    _Pragma("unroll") \
    for (int t_ = 0; t_ < 4; ++t_) { \
        _Pragma("unroll") \
        for (int n_ = 0; n_ < 2; ++n_) { \
            _Pragma("unroll") \
            for (int ks_ = 0; ks_ < 2; ++ks_) \
                acc[(mq)*4 + t_][(nq)*2 + n_] = \
                    __builtin_amdgcn_mfma_f32_16x16x32_bf16( \
                        af[t_][ks_], bf[(nq)*2 + n_][ks_], \
                        acc[(mq)*4 + t_][(nq)*2 + n_], 0, 0, 0); \
        } \
    } \
} while (0)

template <int MODE, int NT>
__global__ __launch_bounds__(512, 2) void gemm_kernel(
        const u16* __restrict__ A, const u16* __restrict__ A2,
        const u16* __restrict__ B, const u16* __restrict__ B2,
        void* __restrict__ Cv, void* __restrict__ Cv2,
        const float* __restrict__ bias, const float* __restrict__ bias2,
        const float* __restrict__ xres, int K,
        int rsA, int rsB, int rsC,
        long long bsA, long long bsB, long long bsC,
        int nx, int ny) {
    const int nwg = 256 * NT;

    // per-tile decode (XCD-chunked bijective swizzle on tile id)
    const u16* tgA[2]; const u16* tgB[2];
    void* tout[2]; const float* tbi[2];
    int tcb[2], tcolb[2], trowb[2];
#pragma unroll
    for (int tt = 0; tt < NT; ++tt) {
        int flat = blockIdx.x + tt * 256;
        int t = (flat & 7) * (nwg >> 3) + (flat >> 3);
        int bx = t % nx, by = (t / nx) % ny, bz = t / (nx * ny);
        int b = bz;
        const u16 *gA, *gB;
        void* out = Cv;
        const float* bi = bias;
        if (MODE == 0) {
            int mat = bz & 1; b = bz >> 1;
            gA = A + (size_t)b * bsA + (size_t)by * 256 * rsA;
            gB = B + (size_t)mat * 262144 + (size_t)bx * 256 * rsB;
            out = mat ? Cv2 : Cv;
            bi = mat ? bias2 : bias;
        } else if (MODE == 2) {
            gA = A + (size_t)b * bsA + (size_t)by * 256 * rsA;
            gB = B + (size_t)b * bsB + (size_t)bx * 256 * rsB;
            out = (b >= 16) ? Cv2 : Cv;
        } else if (MODE == 3) {
            gA = ((b >= 16) ? A2 : A) + (size_t)(b & 15) * bsA + (size_t)by * 256 * rsA;
            gB = B + (size_t)b * bsB + (size_t)bx * 256 * rsB;
            out = (b >= 16) ? Cv2 : Cv;
        } else if (MODE == 4) {
            gA = A + (size_t)by * 256 * rsA;
            gB = ((b >= 16) ? B2 : B) + (size_t)(b & 15) * bsB + (size_t)bx * 256 * rsB;
        } else {  // MODE 1
            gA = A + (size_t)by * 256 * rsA;
            gB = B + (size_t)b * bsB + (size_t)bx * 256 * rsB;
        }
        tgA[tt] = gA; tgB[tt] = gB; tout[tt] = out; tbi[tt] = bi;
        tcb[tt] = (MODE == 2 || MODE == 3) ? (b & 15) : b;
        tcolb[tt] = bx * 256; trowb[tt] = by * 256;
    }

    // 128 KB: [0,16K)=A0 [16K,32K)=B0 [32K,48K)=A1 [48K,64K)=B1  (u16 idx)
    __shared__ __align__(16) u16 smem[65536];

    int tid = threadIdx.x;
    int lane = tid & 63, wave = tid >> 6;
    int wm = wave >> 2, wn = wave & 3;            // 2 x 4 wave grid
    int quad = lane >> 4, l15 = lane & 15, l7 = lane & 7;
    int srow = tid >> 3;                          // 0..63 staging row
    int lg = (tid & 7) ^ (srow & 7);              // pre-swizzled source group

    const int nk = K >> 6;                        // K-tiles (BK=64)
    const int nit = nk >> 1;                      // 2 K-tiles per iteration

    auto STG = [&](const u16* g, int rs, int buf, int isB, int hh, int kt) {
        const u16* src = g + (size_t)(hh * 128 + srow) * rs + (size_t)kt * 64 + lg * 8;
        u16* dst = &smem[buf * 32768 + isB * 16384 + (hh * 128 + srow) * 64 + (tid & 7) * 8];
        gl_lds16(src, dst);
        gl_lds16(src + (size_t)64 * rs, dst + 4096);
    };
    auto LDA = [&](int buf, int mq, int t_, int ks) -> bf16x8 {
        return *(const bf16x8*)&smem[buf * 32768 +
            (wm * 128 + mq * 64 + t_ * 16 + l15) * 64 + (((ks * 4 + quad) ^ l7) << 3)];
    };
    auto LDB = [&](int buf, int nt, int ks) -> bf16x8 {
        return *(const bf16x8*)&smem[buf * 32768 + 16384 +
            (wn * 64 + nt * 16 + l15) * 64 + (((ks * 4 + quad) ^ l7) << 3)];
    };

    f32x4 acc[8][4];
    bf16x8 af[4][2], bf[4][2];

#pragma unroll
    for (int tt = 0; tt < NT; ++tt) {
        const bool hn = (tt + 1 < NT);
        const u16* cA = tgA[tt];
        const u16* cB = tgB[tt];
        const u16* nA = tgA[hn ? tt + 1 : tt];
        const u16* nB = tgB[hn ? tt + 1 : tt];

        if (tt == 0) {
            // cold prologue: buf0 full (tile k0), buf1 B-halves (k1)
            STG(cB, rsB, 0, 1, 0, 0); STG(cB, rsB, 0, 1, 1, 0);
            STG(cA, rsA, 0, 0, 0, 0); STG(cA, rsA, 0, 0, 1, 0);
            STG(cB, rsB, 1, 1, 0, 1); STG(cB, rsB, 1, 1, 1, 1);
            asm volatile("s_waitcnt vmcnt(4)" ::: "memory");
            SCHED(); BAR(); SCHED();
        }

#pragma unroll
        for (int mt = 0; mt < 8; ++mt)
#pragma unroll
            for (int nt = 0; nt < 4; ++nt)
                acc[mt][nt] = (f32x4){0.f, 0.f, 0.f, 0.f};

        for (int it = 0; it < nit; ++it) {
            const bool s = (it + 1 < nit);
            const int k1 = 2 * it + 1, k2 = 2 * it + 2, k3 = 2 * it + 3;

            // phase 1: read af(buf0,mq0)+bf(n0,1); stage A-buf1 (k1) h0
#pragma unroll
            for (int t_ = 0; t_ < 4; ++t_)
#pragma unroll
                for (int ks = 0; ks < 2; ++ks) af[t_][ks] = LDA(0, 0, t_, ks);
#pragma unroll
            for (int n = 0; n < 2; ++n)
#pragma unroll
                for (int ks = 0; ks < 2; ++ks) bf[n][ks] = LDB(0, n, ks);
            STG(cA, rsA, 1, 0, 0, k1);
            SCHED(); BAR(); SCHED();
            __builtin_amdgcn_s_setprio(1); MM(0, 0); __builtin_amdgcn_s_setprio(0);
            SCHED(); BAR(); SCHED();

            // phase 2: read bf(n2,3) buf0; stage A-buf1 (k1) h1
#pragma unroll
            for (int n = 2; n < 4; ++n)
#pragma unroll
                for (int ks = 0; ks < 2; ++ks) bf[n][ks] = LDB(0, n, ks);
            STG(cA, rsA, 1, 0, 1, k1);
            SCHED(); BAR(); SCHED();
            __builtin_amdgcn_s_setprio(1); MM(0, 1); __builtin_amdgcn_s_setprio(0);
            SCHED(); BAR(); SCHED();

            // phase 3: read af(buf0,mq1); stage B-buf0 (k2 | next k0) h0
#pragma unroll
            for (int t_ = 0; t_ < 4; ++t_)
#pragma unroll
                for (int ks = 0; ks < 2; ++ks) af[t_][ks] = LDA(0, 1, t_, ks);
            if (s) STG(cB, rsB, 0, 1, 0, k2);
            else if (hn) STG(nB, rsB, 0, 1, 0, 0);
            SCHED(); BAR(); SCHED();
            __builtin_amdgcn_s_setprio(1); MM(1, 1); __builtin_amdgcn_s_setprio(0);
            SCHED(); BAR(); SCHED();

            // phase 4: stage B-buf0 h1; MFMA; counted vmcnt -> buf1 ready
            if (s) STG(cB, rsB, 0, 1, 1, k2);
            else if (hn) STG(nB, rsB, 0, 1, 1, 0);
            SCHED(); BAR(); SCHED();
            __builtin_amdgcn_s_setprio(1); MM(1, 0); __builtin_amdgcn_s_setprio(0);
            if (s || hn) asm volatile("s_waitcnt vmcnt(4)" ::: "memory");
            else         asm volatile("s_waitcnt vmcnt(0)" ::: "memory");
            SCHED(); BAR(); SCHED();

            // phase 5: read af(buf1,mq0)+bf(n0,1); stage A-buf0 (k2|next k0) h0
#pragma unroll
            for (int t_ = 0; t_ < 4; ++t_)
#pragma unroll
                for (int ks = 0; ks < 2; ++ks) af[t_][ks] = LDA(1, 0, t_, ks);
#pragma unroll
            for (int n = 0; n < 2; ++n)
#pragma unroll
                for (int ks = 0; ks < 2; ++ks) bf[n][ks] = LDB(1, n, ks);
            if (s) STG(cA, rsA, 0, 0, 0, k2);
            else if (hn) STG(nA, rsA, 0, 0, 0, 0);
            SCHED(); BAR(); SCHED();
            __builtin_amdgcn_s_setprio(1); MM(0, 0); __builtin_amdgcn_s_setprio(0);
            SCHED(); BAR(); SCHED();

            // phase 6: read bf(n2,3) buf1; stage A-buf0 h1
#pragma unroll
            for (int n = 2; n < 4; ++n)
#pragma unroll
                for (int ks = 0; ks < 2; ++ks) bf[n][ks] = LDB(1, n, ks);
            if (s) STG(cA, rsA, 0, 0, 1, k2);
            else if (hn) STG(nA, rsA, 0, 0, 1, 0);
            SCHED(); BAR(); SCHED();
            __builtin_amdgcn_s_setprio(1); MM(0, 1); __builtin_amdgcn_s_setprio(0);
            SCHED(); BAR(); SCHED();

            // phase 7: read af(buf1,mq1); stage B-buf1 (k3 | next k1) h0
#pragma unroll
            for (int t_ = 0; t_ < 4; ++t_)
#pragma unroll
                for (int ks = 0; ks < 2; ++ks) af[t_][ks] = LDA(1, 1, t_, ks);
            if (s) STG(cB, rsB, 1, 1, 0, k3);
            else if (hn) STG(nB, rsB, 1, 1, 0, 1);
            SCHED(); BAR(); SCHED();
            __builtin_amdgcn_s_setprio(1); MM(1, 1); __builtin_amdgcn_s_setprio(0);
            SCHED(); BAR(); SCHED();

            // phase 8: stage B-buf1 h1; MFMA; counted vmcnt (steady only)
            if (s) STG(cB, rsB, 1, 1, 1, k3);
            else if (hn) STG(nB, rsB, 1, 1, 1, 1);
            SCHED(); BAR(); SCHED();
            __builtin_amdgcn_s_setprio(1); MM(1, 0); __builtin_amdgcn_s_setprio(0);
            if (s) asm volatile("s_waitcnt vmcnt(4)" ::: "memory");
            SCHED(); BAR(); SCHED();
        }

        // epilogue for tile tt. Scratch lives in buf1-A region [32768,49152):
        // free of reads since phase 7, and junction stages only touch
        // buf0 (A,B) and buf1-B -> no clash with in-flight gl_lds.
        int colb = tcolb[tt] + wn * 64;
        int rowb = trowb[tt] + wm * 128;
        void* out = tout[tt];
        const float* bi_p = tbi[tt];
        int cb = tcb[tt];

        if (MODE == 4) {
            float* ebw = (float*)(smem + 32768) + wave * (16 * ESTRIDE);
            int er = lane >> 4;
            int ec4 = (lane & 15) * 4;
#pragma unroll
            for (int mt = 0; mt < 8; ++mt) {
#pragma unroll
                for (int nt = 0; nt < 4; ++nt) {
                    f32x4 a = acc[mt][nt];
#pragma unroll
                    for (int reg = 0; reg < 4; ++reg)
                        ebw[(quad * 4 + reg) * ESTRIDE + nt * 16 + l15] = a[reg];
                }
#pragma unroll
                for (int j = 0; j < 4; ++j) {
                    int lr = er + 4 * j;
                    f32x2 v0 = *(f32x2*)&ebw[lr * ESTRIDE + ec4];
                    f32x2 v1 = *(f32x2*)&ebw[lr * ESTRIDE + ec4 + 2];
                    int gr = rowb + mt * 16 + lr;
                    int gc = colb + ec4;
                    size_t cidx = (size_t)cb * bsC + (size_t)gr * rsC + gc;
                    float bi = bi_p[gr];
                    float4 xr = *(const float4*)&xres[cidx];
                    float4 st = make_float4(v0.x + bi + xr.x, v0.y + bi + xr.y,
                                            v1.x + bi + xr.z, v1.y + bi + xr.w);
                    *(float4*)&((float*)out)[cidx] = st;
                }
            }
        } else {
            u16* ebw = (smem + 32768) + wave * (16 * ESTRU);
            int er = lane >> 3;            // 0..7
            int ec = (lane & 7) * 8;       // col group
            float bcol[4];
            if (MODE == 0) {
#pragma unroll
                for (int nt = 0; nt < 4; ++nt)
                    bcol[nt] = bi_p[colb + nt * 16 + l15];
            }
#pragma unroll
            for (int mt = 0; mt < 8; ++mt) {
                float4 brow;
                if (MODE == 1)
                    brow = *(const float4*)&bi_p[rowb + mt * 16 + quad * 4];
#pragma unroll
                for (int nt = 0; nt < 4; ++nt) {
                    f32x4 a = acc[mt][nt];
#pragma unroll
                    for (int reg = 0; reg < 4; ++reg) {
                        float fv = a[reg];
                        if (MODE == 0) fv += bcol[nt];
                        else if (MODE == 1) fv += ((const float*)&brow)[reg];
                        else if (MODE == 2) fv *= SCALE;
                        ebw[(quad * 4 + reg) * ESTRU + nt * 16 + l15] = f2bf(fv);
                    }
                }
#pragma unroll
                for (int j = 0; j < 2; ++j) {
                    int lr = er + 8 * j;
                    bf16x8 vv = *(const bf16x8*)&ebw[lr * ESTRU + ec];
                    int gr = rowb + mt * 16 + lr;
                    size_t cidx = (size_t)cb * bsC + (size_t)gr * rsC + colb + ec;
                    *(bf16x8*)&((u16*)out)[cidx] = vv;
                }
            }
        }

        if (hn) {
            // junction: own loads for next tile's buf0 must land (oldest 8 of
            // {8 junction loads + 16 epilogue stores} -> vmcnt(20) covers
            // A-buf0/B-buf0 without draining the stores), then barrier so
            // every wave's wait is observed before buf1-A is overwritten.
            SCHED();
            asm volatile("s_waitcnt vmcnt(20)" ::: "memory");
            BAR(); SCHED();
        }
    }
}

// ------------------------------------------------------------- Softmax
// bf16 S row (1024) -> bf16 P in place. wave-per-row, 4 rows/block.
__global__ __launch_bounds__(256) void softmax_kernel(
        u16* __restrict__ S0, u16* __restrict__ S1) {
    int row = blockIdx.x * 4 + (threadIdx.x >> 6);
    int lane = threadIdx.x & 63;
    u16* p = ((row & 16384) ? S1 : S0) + (size_t)(row & 16383) * N_PIX + lane * 16;
    bf16x8 u0 = *(const bf16x8*)p;
    bf16x8 u1 = *(const bf16x8*)(p + 8);
    float f[16];
#pragma unroll
    for (int i = 0; i < 8; ++i) {
        f[i] = bf2f((u16)u0[i]);
        f[8 + i] = bf2f((u16)u1[i]);
    }
    float m = f[0];
#pragma unroll
    for (int i = 1; i < 16; ++i) m = fmaxf(m, f[i]);
#pragma unroll
    for (int off = 1; off < 64; off <<= 1) m = fmaxf(m, __shfl_xor(m, off));
    float s = 0.f;
#pragma unroll
    for (int i = 0; i < 16; ++i) { f[i] = __expf(f[i] - m); s += f[i]; }
#pragma unroll
    for (int off = 1; off < 64; off <<= 1) s += __shfl_xor(s, off);
    float inv = 1.0f / s;
    bf16x8 s0, s1;
#pragma unroll
    for (int i = 0; i < 8; ++i) {
        s0[i] = (short)f2bf(f[i] * inv);
        s1[i] = (short)f2bf(f[8 + i] * inv);
    }
    *(bf16x8*)p = s0;
    *(bf16x8*)(p + 8) = s1;
}

extern "C" void kernel_launch(void* const* d_in, const int* in_sizes, int n_in,
                              void* d_out, int out_size, void* d_ws, size_t ws_size,
                              hipStream_t stream) {
    const float* x    = (const float*)d_in[0];
    const float* gn_w = (const float*)d_in[1];
    const float* gn_b = (const float*)d_in[2];
    const float* wq   = (const float*)d_in[3];
    const float* bq   = (const float*)d_in[4];
    const float* wk   = (const float*)d_in[5];
    const float* bk   = (const float*)d_in[6];
    const float* wv   = (const float*)d_in[7];
    const float* bv   = (const float*)d_in[8];
    const float* wp   = (const float*)d_in[9];
    const float* bp   = (const float*)d_in[10];
    float* y = (float*)d_out;

    const size_t BCN = (size_t)BATCH * C_DIM * N_PIX;
    char* w = (char*)d_ws;
    u16* h  = (u16*)(w);                       // reused as S0
    u16* q  = (u16*)(w + 2 * BCN);             // reused as O0
    u16* k  = (u16*)(w + 4 * BCN);             // reused as O1
    u16* v  = (u16*)(w + 6 * BCN);
    u16* Or = (u16*)(w + 8 * BCN);             // reused as S1
    u16* wb = (u16*)(w + 10 * BCN);            // 2 MB bf16 weights
    u16* wvb = wb + 524288, *wpb = wb + 786432;
    float* stats = (float*)(w + 10 * BCN + 2 * 1024 * 1024);   // 8 KB
    u16* S0 = h;
    u16* S1 = Or;
    u16* O0 = q;
    u16* O1 = k;

    const long long BS = 524288;               // per-batch elems
    const long long SB = 1048576;              // per-batch S elems

    prep_kernel<<<2048, 256, 0, stream>>>(wq, wk, wv, wp, wb, x, stats);
    gnt_kernel<<<512, 256, 0, stream>>>(x, gn_w, gn_b, stats, h);

    // q,k[n][o] = h[n][c]*w[o][c] + b[o]   M=1024 N=512 K=512, 512 tiles
    gemm_kernel<0, 2><<<256, 512, 0, stream>>>(
        h, nullptr, wb, nullptr, q, k, bq, bk, nullptr,
        512, 512, 512, 512, BS, 0, BS, 2, 4);
    // v[c][n] = wv[c][c']*h[n][c'] + bv[c]  M=512 N=1024 K=512
    gemm_kernel<1, 1><<<256, 512, 0, stream>>>(
        wvb, nullptr, h, nullptr, v, nullptr, bv, nullptr, nullptr,
        512, 512, 512, 1024, 0, BS, BS, 4, 2);

    // S[i][j] = SCALE * q[i][o]*k[j][o]  M=N=1024 K=512, 512 tiles
    gemm_kernel<2, 2><<<256, 512, 0, stream>>>(
        q, nullptr, k, nullptr, S0, S1, nullptr, nullptr, nullptr,
        512, 512, 512, 1024, BS, BS, SB, 4, 4);
    softmax_kernel<<<8192, 256, 0, stream>>>(S0, S1);
    // O[i][c] = P[i][j]*v[c][j]  M=1024 N=512 K=1024
    gemm_kernel<3, 1><<<256, 512, 0, stream>>>(
        S0, S1, v, nullptr, O0, O1, nullptr, nullptr, nullptr,
        1024, 1024, 1024, 512, SB, BS, BS, 2, 4);

    // y[o][n] = x + bp[o] + wp[o][c]*O[n][c]  M=512 N=1024 K=512
    gemm_kernel<4, 1><<<256, 512, 0, stream>>>(
        wpb, nullptr, O0, O1, y, nullptr, bp, nullptr, x,
        512, 512, 512, 1024, 0, BS, BS, 4, 2);
}